// Round 1
// baseline (76.669 us; speedup 1.0000x reference)
//
#include <hip/hip_runtime.h>

// FK loss: B=262144 elements, 7-DOF DH chain -> (pos, rpy) -> MSE vs poses.
// One thread per element; compile-time-folded alpha constants; block-level
// reduction + one atomicAdd per block.

#define FK_B 262144

// In-place update: T <- T * A(ct, st, d, a, cal, sal)
// T kept as R (3x3) and p (3); A's bottom row is [0,0,0,1].
__device__ __forceinline__ void dh_step(float R[3][3], float p[3],
                                        float ct, float st,
                                        float d, float a,
                                        float cal, float sal) {
    // Columns of A's rotation block
    const float c0x = ct,        c0y = st,        c0z = 0.0f;
    const float c1x = -st * cal, c1y = ct * cal,  c1z = sal;
    const float c2x = st * sal,  c2y = -ct * sal, c2z = cal;
    const float px = a * ct, py = a * st, pz = d;

    float nR[3][3], np[3];
#pragma unroll
    for (int r = 0; r < 3; ++r) {
        nR[r][0] = R[r][0] * c0x + R[r][1] * c0y + R[r][2] * c0z;
        nR[r][1] = R[r][0] * c1x + R[r][1] * c1y + R[r][2] * c1z;
        nR[r][2] = R[r][0] * c2x + R[r][1] * c2y + R[r][2] * c2z;
        np[r]    = R[r][0] * px  + R[r][1] * py  + R[r][2] * pz + p[r];
    }
#pragma unroll
    for (int r = 0; r < 3; ++r) {
        R[r][0] = nR[r][0]; R[r][1] = nR[r][1]; R[r][2] = nR[r][2];
        p[r] = np[r];
    }
}

__global__ __launch_bounds__(256) void fk_loss_kernel(
    const float* __restrict__ joints,   // (B,7)
    const float* __restrict__ poses,    // (B,6)
    float* __restrict__ out)            // scalar
{
    const int i = blockIdx.x * blockDim.x + threadIdx.x;

    float q[7];
#pragma unroll
    for (int k = 0; k < 7; ++k) q[k] = joints[i * 7 + k];

    float s[7], c[7];
#pragma unroll
    for (int k = 0; k < 7; ++k) sincosf(q[k], &s[k], &c[k]);

    // T = A0: d=0.333, a=0, alpha=0 (cal=1, sal=0)
    float R[3][3] = {{c[0], -s[0], 0.0f},
                     {s[0],  c[0], 0.0f},
                     {0.0f,  0.0f, 1.0f}};
    float p[3] = {0.0f, 0.0f, 0.333f};

    //            ct    st     d       a        cal   sal
    dh_step(R, p, c[1], s[1], 0.0f,   0.0f,    0.0f, -1.0f);  // al=-pi/2
    dh_step(R, p, c[2], s[2], 0.316f, 0.0f,    0.0f,  1.0f);  // al=+pi/2
    dh_step(R, p, c[3], s[3], 0.0f,   0.0825f, 0.0f,  1.0f);  // al=+pi/2
    dh_step(R, p, c[4], s[4], 0.384f,-0.0825f, 0.0f, -1.0f);  // al=-pi/2
    dh_step(R, p, c[5], s[5], 0.0f,   0.0f,    0.0f,  1.0f);  // al=+pi/2
    dh_step(R, p, c[6], s[6], 0.107f, 0.088f,  0.0f,  1.0f);  // al=+pi/2

    float fk[6];
    fk[0] = p[0]; fk[1] = p[1]; fk[2] = p[2];
    fk[3] = atan2f(-R[1][2], R[2][2]);
    float r02 = fminf(1.0f, fmaxf(-1.0f, R[0][2]));
    fk[4] = asinf(r02);
    fk[5] = atan2f(-R[0][1], R[0][0]);

    float err = 0.0f;
#pragma unroll
    for (int k = 0; k < 6; ++k) {
        float dlt = fk[k] - poses[i * 6 + k];
        err += dlt * dlt;
    }

    // wave-64 reduction
#pragma unroll
    for (int off = 32; off > 0; off >>= 1)
        err += __shfl_down(err, off, 64);

    __shared__ float wsum[4];
    const int lane = threadIdx.x & 63;
    const int wid  = threadIdx.x >> 6;
    if (lane == 0) wsum[wid] = err;
    __syncthreads();
    if (threadIdx.x == 0) {
        float v = wsum[0] + wsum[1] + wsum[2] + wsum[3];
        atomicAdd(out, v * (1.0f / (FK_B * 6.0f)));
    }
}

extern "C" void kernel_launch(void* const* d_in, const int* in_sizes, int n_in,
                              void* d_out, int out_size, void* d_ws, size_t ws_size,
                              hipStream_t stream) {
    const float* joints = (const float*)d_in[0];
    const float* poses  = (const float*)d_in[1];
    float* out = (float*)d_out;

    // d_out is poisoned (0xAA) before every timed launch -> zero it.
    hipMemsetAsync(out, 0, sizeof(float), stream);

    fk_loss_kernel<<<FK_B / 256, 256, 0, stream>>>(joints, poses, out);
}

// Round 2
// 66.696 us; speedup vs baseline: 1.1495x; 1.1495x over previous
//
#include <hip/hip_runtime.h>

// FK loss: B=262144, 7-DOF DH chain -> (pos, rpy) -> MSE vs poses.
// R2: fast HW trig (__sinf/__cosf, inputs are N(0,1) so no range issue),
//     two-stage reduction via d_ws (no memset, no same-address atomics).

#define FK_B 262144
#define NBLK (FK_B / 256)   // 1024 partial sums

// In-place update: T <- T * A(ct, st, d, a, cal, sal); bottom row [0,0,0,1].
__device__ __forceinline__ void dh_step(float R[3][3], float p[3],
                                        float ct, float st,
                                        float d, float a,
                                        float cal, float sal) {
    const float c0x = ct,        c0y = st,        c0z = 0.0f;
    const float c1x = -st * cal, c1y = ct * cal,  c1z = sal;
    const float c2x = st * sal,  c2y = -ct * sal, c2z = cal;
    const float px = a * ct, py = a * st, pz = d;

    float nR[3][3], np[3];
#pragma unroll
    for (int r = 0; r < 3; ++r) {
        nR[r][0] = R[r][0] * c0x + R[r][1] * c0y + R[r][2] * c0z;
        nR[r][1] = R[r][0] * c1x + R[r][1] * c1y + R[r][2] * c1z;
        nR[r][2] = R[r][0] * c2x + R[r][1] * c2y + R[r][2] * c2z;
        np[r]    = R[r][0] * px  + R[r][1] * py  + R[r][2] * pz + p[r];
    }
#pragma unroll
    for (int r = 0; r < 3; ++r) {
        R[r][0] = nR[r][0]; R[r][1] = nR[r][1]; R[r][2] = nR[r][2];
        p[r] = np[r];
    }
}

__global__ __launch_bounds__(256) void fk_loss_kernel(
    const float* __restrict__ joints,   // (B,7)
    const float* __restrict__ poses,    // (B,6)
    float* __restrict__ partials)       // (NBLK,)
{
    const int i = blockIdx.x * blockDim.x + threadIdx.x;

    float q[7];
#pragma unroll
    for (int k = 0; k < 7; ++k) q[k] = joints[i * 7 + k];

    float s[7], c[7];
#pragma unroll
    for (int k = 0; k < 7; ++k) {
        s[k] = __sinf(q[k]);   // v_sin_f32 path; |q| < ~6 so fully accurate
        c[k] = __cosf(q[k]);
    }

    // T = A0: d=0.333, a=0, alpha=0
    float R[3][3] = {{c[0], -s[0], 0.0f},
                     {s[0],  c[0], 0.0f},
                     {0.0f,  0.0f, 1.0f}};
    float p[3] = {0.0f, 0.0f, 0.333f};

    //            ct    st     d       a        cal   sal
    dh_step(R, p, c[1], s[1], 0.0f,   0.0f,    0.0f, -1.0f);  // al=-pi/2
    dh_step(R, p, c[2], s[2], 0.316f, 0.0f,    0.0f,  1.0f);  // al=+pi/2
    dh_step(R, p, c[3], s[3], 0.0f,   0.0825f, 0.0f,  1.0f);  // al=+pi/2
    dh_step(R, p, c[4], s[4], 0.384f,-0.0825f, 0.0f, -1.0f);  // al=-pi/2
    dh_step(R, p, c[5], s[5], 0.0f,   0.0f,    0.0f,  1.0f);  // al=+pi/2
    dh_step(R, p, c[6], s[6], 0.107f, 0.088f,  0.0f,  1.0f);  // al=+pi/2

    float fk[6];
    fk[0] = p[0]; fk[1] = p[1]; fk[2] = p[2];
    fk[3] = atan2f(-R[1][2], R[2][2]);
    float r02 = fminf(1.0f, fmaxf(-1.0f, R[0][2]));
    fk[4] = asinf(r02);
    fk[5] = atan2f(-R[0][1], R[0][0]);

    float err = 0.0f;
#pragma unroll
    for (int k = 0; k < 6; ++k) {
        float dlt = fk[k] - poses[i * 6 + k];
        err += dlt * dlt;
    }

    // wave-64 butterfly-free reduction
#pragma unroll
    for (int off = 32; off > 0; off >>= 1)
        err += __shfl_down(err, off, 64);

    __shared__ float wsum[4];
    const int lane = threadIdx.x & 63;
    const int wid  = threadIdx.x >> 6;
    if (lane == 0) wsum[wid] = err;
    __syncthreads();
    if (threadIdx.x == 0)
        partials[blockIdx.x] = wsum[0] + wsum[1] + wsum[2] + wsum[3];
}

__global__ __launch_bounds__(256) void fk_reduce_kernel(
    const float* __restrict__ partials,  // (NBLK,)
    float* __restrict__ out)             // scalar
{
    const int t = threadIdx.x;
    float v = 0.0f;
#pragma unroll
    for (int k = 0; k < NBLK / 256; ++k)
        v += partials[t + k * 256];

#pragma unroll
    for (int off = 32; off > 0; off >>= 1)
        v += __shfl_down(v, off, 64);

    __shared__ float wsum[4];
    const int lane = t & 63;
    const int wid  = t >> 6;
    if (lane == 0) wsum[wid] = v;
    __syncthreads();
    if (t == 0)
        out[0] = (wsum[0] + wsum[1] + wsum[2] + wsum[3]) * (1.0f / (FK_B * 6.0f));
}

extern "C" void kernel_launch(void* const* d_in, const int* in_sizes, int n_in,
                              void* d_out, int out_size, void* d_ws, size_t ws_size,
                              hipStream_t stream) {
    const float* joints = (const float*)d_in[0];
    const float* poses  = (const float*)d_in[1];
    float* out      = (float*)d_out;
    float* partials = (float*)d_ws;   // poisoned each iter, but fully overwritten

    fk_loss_kernel<<<NBLK, 256, 0, stream>>>(joints, poses, partials);
    fk_reduce_kernel<<<1, 256, 0, stream>>>(partials, out);
}

// Round 3
// 66.443 us; speedup vs baseline: 1.1539x; 1.0038x over previous
//
#include <hip/hip_runtime.h>

// FK loss: B=262144, 7-DOF DH chain -> (pos, rpy) -> MSE vs poses.
// R3: branchless Cephes atan2 (err ~1e-7 rad), asin via atan2(x, sqrt(1-x^2)),
//     __sinf/__cosf HW trig. Two-stage reduction through d_ws.

#define FK_B 262144
#define NBLK (FK_B / 256)   // 1024 partial sums

// Branchless atan2, Cephes-style. Max error ~1e-7 rad. No libm call.
__device__ __forceinline__ float fast_atan2f(float y, float x) {
    const float ax = fabsf(x), ay = fabsf(y);
    const float mx = fmaxf(ax, ay);
    const float mn = fminf(ax, ay);
    float t = __fdividef(mn, fmaxf(mx, 1e-30f));      // [0,1]
    const bool red = t > 0.41421356f;                  // tan(pi/8)
    const float tr = __fdividef(t - 1.0f, t + 1.0f);   // range-reduce
    float u = red ? tr : t;                            // |u| <= 0.41422
    const float s = u * u;
    float p = fmaf(s, 8.05374449538e-2f, -1.38776856032e-1f);
    p = fmaf(s, p, 1.99777106478e-1f);
    p = fmaf(s, p, -3.33329491539e-1f);
    float r = fmaf(u * s, p, u);
    if (red) r += 0.78539816340f;                      // + pi/4
    if (ay > ax) r = 1.57079632679f - r;               // octant fold
    if (x < 0.0f) r = 3.14159265359f - r;              // quadrant fold
    return copysignf(r, y);
}

// In-place update: T <- T * A(ct, st, d, a, cal, sal); bottom row [0,0,0,1].
__device__ __forceinline__ void dh_step(float R[3][3], float p[3],
                                        float ct, float st,
                                        float d, float a,
                                        float cal, float sal) {
    const float c0x = ct,        c0y = st,        c0z = 0.0f;
    const float c1x = -st * cal, c1y = ct * cal,  c1z = sal;
    const float c2x = st * sal,  c2y = -ct * sal, c2z = cal;
    const float px = a * ct, py = a * st, pz = d;

    float nR[3][3], np[3];
#pragma unroll
    for (int r = 0; r < 3; ++r) {
        nR[r][0] = R[r][0] * c0x + R[r][1] * c0y + R[r][2] * c0z;
        nR[r][1] = R[r][0] * c1x + R[r][1] * c1y + R[r][2] * c1z;
        nR[r][2] = R[r][0] * c2x + R[r][1] * c2y + R[r][2] * c2z;
        np[r]    = R[r][0] * px  + R[r][1] * py  + R[r][2] * pz + p[r];
    }
#pragma unroll
    for (int r = 0; r < 3; ++r) {
        R[r][0] = nR[r][0]; R[r][1] = nR[r][1]; R[r][2] = nR[r][2];
        p[r] = np[r];
    }
}

__global__ __launch_bounds__(256) void fk_loss_kernel(
    const float* __restrict__ joints,   // (B,7)
    const float* __restrict__ poses,    // (B,6)
    float* __restrict__ partials)       // (NBLK,)
{
    const int i = blockIdx.x * blockDim.x + threadIdx.x;

    float s[7], c[7];
#pragma unroll
    for (int k = 0; k < 7; ++k) {
        const float q = joints[i * 7 + k];
        s[k] = __sinf(q);   // HW v_sin path; |q| ~ N(0,1), fully accurate
        c[k] = __cosf(q);
    }

    // T = A0: d=0.333, a=0, alpha=0
    float R[3][3] = {{c[0], -s[0], 0.0f},
                     {s[0],  c[0], 0.0f},
                     {0.0f,  0.0f, 1.0f}};
    float p[3] = {0.0f, 0.0f, 0.333f};

    //            ct    st     d       a        cal   sal
    dh_step(R, p, c[1], s[1], 0.0f,   0.0f,    0.0f, -1.0f);  // al=-pi/2
    dh_step(R, p, c[2], s[2], 0.316f, 0.0f,    0.0f,  1.0f);  // al=+pi/2
    dh_step(R, p, c[3], s[3], 0.0f,   0.0825f, 0.0f,  1.0f);  // al=+pi/2
    dh_step(R, p, c[4], s[4], 0.384f,-0.0825f, 0.0f, -1.0f);  // al=-pi/2
    dh_step(R, p, c[5], s[5], 0.0f,   0.0f,    0.0f,  1.0f);  // al=+pi/2
    dh_step(R, p, c[6], s[6], 0.107f, 0.088f,  0.0f,  1.0f);  // al=+pi/2

    float fk[6];
    fk[0] = p[0]; fk[1] = p[1]; fk[2] = p[2];
    fk[3] = fast_atan2f(-R[1][2], R[2][2]);
    const float r02 = fminf(1.0f, fmaxf(-1.0f, R[0][2]));
    fk[4] = fast_atan2f(r02, sqrtf(fmaxf(0.0f, 1.0f - r02 * r02)));  // asin
    fk[5] = fast_atan2f(-R[0][1], R[0][0]);

    float err = 0.0f;
#pragma unroll
    for (int k = 0; k < 6; ++k) {
        float dlt = fk[k] - poses[i * 6 + k];
        err += dlt * dlt;
    }

    // wave-64 reduction
#pragma unroll
    for (int off = 32; off > 0; off >>= 1)
        err += __shfl_down(err, off, 64);

    __shared__ float wsum[4];
    const int lane = threadIdx.x & 63;
    const int wid  = threadIdx.x >> 6;
    if (lane == 0) wsum[wid] = err;
    __syncthreads();
    if (threadIdx.x == 0)
        partials[blockIdx.x] = wsum[0] + wsum[1] + wsum[2] + wsum[3];
}

__global__ __launch_bounds__(256) void fk_reduce_kernel(
    const float* __restrict__ partials,  // (NBLK,)
    float* __restrict__ out)             // scalar
{
    const int t = threadIdx.x;
    float v = 0.0f;
#pragma unroll
    for (int k = 0; k < NBLK / 256; ++k)
        v += partials[t + k * 256];

#pragma unroll
    for (int off = 32; off > 0; off >>= 1)
        v += __shfl_down(v, off, 64);

    __shared__ float wsum[4];
    const int lane = t & 63;
    const int wid  = t >> 6;
    if (lane == 0) wsum[wid] = v;
    __syncthreads();
    if (t == 0)
        out[0] = (wsum[0] + wsum[1] + wsum[2] + wsum[3]) * (1.0f / (FK_B * 6.0f));
}

extern "C" void kernel_launch(void* const* d_in, const int* in_sizes, int n_in,
                              void* d_out, int out_size, void* d_ws, size_t ws_size,
                              hipStream_t stream) {
    const float* joints = (const float*)d_in[0];
    const float* poses  = (const float*)d_in[1];
    float* out      = (float*)d_out;
    float* partials = (float*)d_ws;   // poisoned each iter, fully overwritten

    fk_loss_kernel<<<NBLK, 256, 0, stream>>>(joints, poses, partials);
    fk_reduce_kernel<<<1, 256, 0, stream>>>(partials, out);
}